// Round 15
// baseline (148.305 us; speedup 1.0000x reference)
//
#include <hip/hip_runtime.h>

typedef __attribute__((ext_vector_type(8))) short bf16x8;
typedef __attribute__((ext_vector_type(4))) float f32x4;
typedef __attribute__((ext_vector_type(4))) unsigned uint4v;

#define SM_C 0.18033688011112042f  // 0.125 * log2(e)
#define SM_M 20.0f                 // static softmax shift (exact; f32 overflow needs s>730)
#define MFMA16 __builtin_amdgcn_mfma_f32_16x16x32_bf16

__device__ __forceinline__ unsigned short f2bf(float f) {
  unsigned u = __builtin_bit_cast(unsigned, f);
  u += 0x7fffu + ((u >> 16) & 1u);
  return (unsigned short)(u >> 16);
}

__device__ __forceinline__ unsigned cvtpk(float lo, float hi) {
  unsigned r;
  asm volatile("v_cvt_pk_bf16_f32 %0, %1, %2" : "=v"(r) : "v"(lo), "v"(hi));
  return r;
}

__device__ __forceinline__ void gload16(const void* g, void* lds) {
  __builtin_amdgcn_global_load_lds(
      (const __attribute__((address_space(1))) void*)g,
      (__attribute__((address_space(3))) void*)lds, 16, 0, 0);
}

#define BARRIER __builtin_amdgcn_s_barrier()
#define LGKM0 asm volatile("s_waitcnt lgkmcnt(0)" ::: "memory")
#define VM0 asm volatile("s_waitcnt vmcnt(0)" ::: "memory")

// ---------------- prep: x->bf16 (blocks 0..2047) + 4x W transpose ----------
__global__ __launch_bounds__(256) void prep(const float* __restrict__ x,
                                            unsigned short* __restrict__ xb,
                                            const float* __restrict__ W0,
                                            const float* __restrict__ W1,
                                            const float* __restrict__ W2,
                                            const float* __restrict__ W3,
                                            unsigned short* __restrict__ WT) {
  __shared__ float tile[32][33];
  const int bid = blockIdx.x;
  if (bid < 2048) {
    int i = bid * 256 + threadIdx.x;
    for (; i < 2097152; i += 2048 * 256) {
      float4 v = ((const float4*)x)[i];
      unsigned long long packed = (unsigned long long)f2bf(v.x) |
                                  ((unsigned long long)f2bf(v.y) << 16) |
                                  ((unsigned long long)f2bf(v.z) << 32) |
                                  ((unsigned long long)f2bf(v.w) << 48);
      ((unsigned long long*)xb)[i] = packed;
    }
  } else {
    int b2 = bid - 2048;
    const int z = b2 >> 10;
    b2 &= 1023;
    const int bx = b2 & 31, by = b2 >> 5;
    const float* W = (z == 0) ? W0 : (z == 1) ? W1 : (z == 2) ? W2 : W3;
    unsigned short* WTo = WT + (size_t)z * 1048576;
    const int tx = threadIdx.x & 31, ty = threadIdx.x >> 5;
    const int xcol = bx * 32 + tx;
    for (int i = 0; i < 4; ++i) {
      int r = ty + i * 8;
      tile[r][tx] = W[(by * 32 + r) * 1024 + xcol];
    }
    __syncthreads();
    const int nx = by * 32 + tx;
    for (int i = 0; i < 4; ++i) {
      int r = ty + i * 8;
      WTo[(long)(bx * 32 + r) * 1024 + nx] = f2bf(tile[tx][r]);
    }
  }
}

// ---------------- GEMM (m97-style, 128x128, BK=64, 2 blocks/CU) -------------
// C[M][N] = A[M][K] * BT[N][K]^T.  256 thr = 4 waves (2M x 2N), wave 64x64.
// Per K-tile: STAGE(t+1) -> 16 ds_read_b128 -> lgkm0 -> 32 MFMA (setprio)
// -> vmcnt(0) -> ONE barrier.  Hazards: stage into buf^1 is safe because all
// waves' reads of buf^1 (tile t-1) completed via their lgkm0 before tile t's
// entry barrier; next tile's reads of buf^1 are gated by vmcnt(0)+barrier.
// LDS 64KB/block -> 2 independent blocks/CU (inter-block overlap, m114).
// MODE 0: Q/K plane stores or V^T key-permuted scatter (routed per tn).
// MODE 1: f32 + bias.
template <int MODE>
__global__ __launch_bounds__(256) void gemm97(const unsigned short* __restrict__ A,
                                              const unsigned short* __restrict__ BT,
                                              unsigned short* __restrict__ Cb,
                                              float* __restrict__ Cf,
                                              const float* __restrict__ bias,
                                              int M, int N, int K) {
  __shared__ alignas(16) unsigned short As[2][128 * 64];
  __shared__ alignas(16) unsigned short Bs[2][128 * 64];

  const int nbn = N >> 7;
  const int tmg = (M >> 7) >> 3;   // tiles per XCD row-group
  const int cc = blockIdx.x >> 3, xc = blockIdx.x & 7;
  const int tm = xc * tmg + cc / nbn, tn = cc % nbn;

  const int t = threadIdx.x, l = t & 63, wid = t >> 6;
  const int wm = wid >> 1, wn = wid & 1;
  const int lr = l & 15, lg = l >> 4;

  f32x4 acc[4][4] = {};

  // staging: thread t covers (row q*32+sq, slot t&7); source pre-swizzled
  // (slot ^ row&7), LDS dest linear (rule 21).  row&7 == sq&7.
  const int sq = t >> 3;           // 0..31
  const int sslot8 = ((t & 7) ^ (sq & 7)) * 8;
  const unsigned short* Ath = A + ((long)tm * 128 + sq) * K + sslot8;
  const unsigned short* Bth = BT + ((long)tn * 128 + sq) * K + sslot8;
  const int ldsoff = sq * 64 + (t & 7) * 8;

#define STG(buf, kt)                                                      \
  do {                                                                    \
    _Pragma("unroll") for (int q_ = 0; q_ < 4; ++q_) {                    \
      gload16(Ath + (long)(q_ * 32) * K + (kt) * 64,                      \
              &As[buf][q_ * 2048 + ldsoff]);                              \
      gload16(Bth + (long)(q_ * 32) * K + (kt) * 64,                      \
              &Bs[buf][q_ * 2048 + ldsoff]);                              \
    }                                                                     \
  } while (0)

  const int NT = K >> 6;
  STG(0, 0);
  VM0;
  BARRIER;

  const int offk0 = (lg ^ (lr & 7)) * 8;
  const int offk1 = ((4 + lg) ^ (lr & 7)) * 8;
  const int arow0 = (wm * 64 + lr) * 64;
  const int brow0 = (wn * 64 + lr) * 64;

  for (int tt = 0; tt < NT; ++tt) {
    const int cur = tt & 1;
    if (tt + 1 < NT) STG(cur ^ 1, tt + 1);

    const unsigned short* Ac = As[cur];
    const unsigned short* Bc = Bs[cur];
    bf16x8 af[4][2], bfr[4][2];
#pragma unroll
    for (int m = 0; m < 4; ++m) {
      const unsigned short* ap = Ac + arow0 + m * 1024;
      af[m][0] = *(const bf16x8*)(ap + offk0);
      af[m][1] = *(const bf16x8*)(ap + offk1);
    }
#pragma unroll
    for (int n = 0; n < 4; ++n) {
      const unsigned short* bp = Bc + brow0 + n * 1024;
      bfr[n][0] = *(const bf16x8*)(bp + offk0);
      bfr[n][1] = *(const bf16x8*)(bp + offk1);
    }
    LGKM0;
    __builtin_amdgcn_s_setprio(1);
#pragma unroll
    for (int m = 0; m < 4; ++m)
#pragma unroll
      for (int n = 0; n < 4; ++n) {
        acc[m][n] = MFMA16(af[m][0], bfr[n][0], acc[m][n], 0, 0, 0);
        acc[m][n] = MFMA16(af[m][1], bfr[n][1], acc[m][n], 0, 0, 0);
      }
    __builtin_amdgcn_s_setprio(0);

    if (tt + 1 < NT) {
      VM0;      // tile t+1's stages landed (cheap: issued before ds+MFMA)
      BARRIER;  // all waves' reads of buf[cur] also done (each via lgkm0)
    }
  }
#undef STG

  const long crow = (long)tm * 128 + wm * 64;
  const int ccolw = wn * 64;

  if constexpr (MODE == 1) {
#pragma unroll
    for (int m = 0; m < 4; ++m)
#pragma unroll
      for (int n = 0; n < 4; ++n)
#pragma unroll
        for (int r = 0; r < 4; ++r) {
          long row = crow + m * 16 + lg * 4 + r;
          int col = tn * 128 + ccolw + n * 16 + lr;
          Cf[row * N + col] = acc[m][n][r] + bias[col];
        }
  } else {
    if (tn < 16) {
      // Q plane (tn 0-7) or K plane (tn 8-15), stride 1024
      unsigned short* pl = Cb + ((tn < 8) ? 0 : 8388608);
      const int pc = (tn & 7) * 128 + ccolw + lr;
#pragma unroll
      for (int m = 0; m < 4; ++m)
#pragma unroll
        for (int n = 0; n < 4; ++n)
#pragma unroll
          for (int r = 0; r < 4; ++r) {
            long row = crow + m * 16 + lg * 4 + r;
            pl[row * 1024 + pc + n * 16] = f2bf(acc[m][n][r]);
          }
    } else {
      // V^T plane, key permutation: Vt[(b*16+h)*64+hd][2048 s-perm]
      unsigned short* VtW = Cb + 16777216;
      const int bq = (tm >> 4) << 4;                 // b*16
      const int sbase = ((tm & 15) << 7) + wm * 64;  // s within batch
#pragma unroll
      for (int m = 0; m < 4; ++m) {
        const int srow_ = sbase + m * 16 + lg * 4;
        const int lwb = srow_ & 63;
        const int stt = srow_ >> 6;
        const int vp0 = (lwb & 32) | (((lwb >> 2) & 3) << 3) | (((lwb >> 4) & 1) << 2);
#pragma unroll
        for (int n = 0; n < 4; ++n) {
          const int vcol = (tn - 16) * 128 + ccolw + n * 16 + lr;
          const long vtrow = (long)(bq + (vcol >> 6)) * 64 + (vcol & 63);
          unsigned long long pk4 =
              (unsigned long long)f2bf(acc[m][n][0]) |
              ((unsigned long long)f2bf(acc[m][n][1]) << 16) |
              ((unsigned long long)f2bf(acc[m][n][2]) << 32) |
              ((unsigned long long)f2bf(acc[m][n][3]) << 48);
          *(unsigned long long*)(VtW + vtrow * 2048 + stt * 64 + vp0) = pk4;
        }
      }
    }
  }
}

// ---------------- Flash attention tile body (static-max, scalar accum) ------
template <int TWO>
__device__ __forceinline__ void attn_tile(
    const unsigned short* __restrict__ Kc, const unsigned short* __restrict__ Vc,
    int lr, int lg, bool mask0, bool mask1, int kv0, int q0row, int q1row,
    const bf16x8 (&qf)[2][2], f32x4 (&cacc)[2][4], float (&l_r)[2]) {
  constexpr int S0 = TWO ? 0 : 1;
  f32x4 p[2][4];
#pragma unroll
  for (int s = S0; s < 2; ++s)
#pragma unroll
    for (int g = 0; g < 4; ++g) p[s][g] = f32x4{0.f, 0.f, 0.f, 0.f};

  __builtin_amdgcn_s_setprio(1);
#pragma unroll
  for (int g = 0; g < 4; ++g) {
    const int key = g * 16 + lr;
    const int swz = (key & 7) << 3;
#pragma unroll
    for (int c = 0; c < 2; ++c) {
      bf16x8 kf = *(const bf16x8*)(Kc + key * 64 + ((c * 32 + lg * 8) ^ swz));
#pragma unroll
      for (int s = S0; s < 2; ++s)
        p[s][g] = MFMA16(kf, qf[s][c], p[s][g], 0, 0, 0);
    }
  }
  __builtin_amdgcn_s_setprio(0);

  if (TWO && mask0) {
#pragma unroll
    for (int g = 0; g < 4; ++g)
#pragma unroll
      for (int r = 0; r < 4; ++r)
        if (kv0 + g * 16 + lg * 4 + r > q0row) p[0][g][r] = -1e30f;
  }
  if (mask1) {
#pragma unroll
    for (int g = 0; g < 4; ++g)
#pragma unroll
      for (int r = 0; r < 4; ++r)
        if (kv0 + g * 16 + lg * 4 + r > q1row) p[1][g][r] = -1e30f;
  }

  const float SM_NMC = -SM_M * SM_C;
  unsigned pk[2][4][2];
#pragma unroll
  for (int s = S0; s < 2; ++s) {
    float e[4][4];
#pragma unroll
    for (int g = 0; g < 4; ++g)
#pragma unroll
      for (int r = 0; r < 4; ++r)
        e[g][r] = __builtin_amdgcn_exp2f(__builtin_fmaf(p[s][g][r], SM_C, SM_NMC));
    float t0 = (e[0][0] + e[0][1]) + (e[0][2] + e[0][3]);
    float t1 = (e[1][0] + e[1][1]) + (e[1][2] + e[1][3]);
    float t2 = (e[2][0] + e[2][1]) + (e[2][2] + e[2][3]);
    float t3 = (e[3][0] + e[3][1]) + (e[3][2] + e[3][3]);
    l_r[s] += (t0 + t1) + (t2 + t3);
#pragma unroll
    for (int g = 0; g < 4; ++g) {
      pk[s][g][0] = cvtpk(e[g][0], e[g][1]);
      pk[s][g][1] = cvtpk(e[g][2], e[g][3]);
    }
  }

#pragma unroll
  for (int sl = 0; sl < 2; ++sl) {
    bf16x8 vf[4];
#pragma unroll
    for (int n = 0; n < 4; ++n) {
      const int hd = n * 16 + lr;
      vf[n] = *(const bf16x8*)(Vc + hd * 64 + ((sl * 32 + lg * 8) ^ ((hd & 7) << 3)));
    }
    __builtin_amdgcn_s_setprio(1);
#pragma unroll
    for (int s = S0; s < 2; ++s) {
      uint4v pw = {pk[s][2 * sl][0], pk[s][2 * sl][1], pk[s][2 * sl + 1][0], pk[s][2 * sl + 1][1]};
      bf16x8 pa = __builtin_bit_cast(bf16x8, pw);
#pragma unroll
      for (int n = 0; n < 4; ++n)
        cacc[s][n] = MFMA16(pa, vf[n], cacc[s][n], 0, 0, 0);
    }
    __builtin_amdgcn_s_setprio(0);
  }
}

// ---------------- Flash attention (paired strips, counted-vmcnt pipeline) ---
__global__ __launch_bounds__(256, 4) void flash_attn(const unsigned short* __restrict__ Qp,
                                                     const unsigned short* __restrict__ Kp,
                                                     const unsigned short* __restrict__ Vt,
                                                     unsigned short* __restrict__ Ctx) {
  __shared__ alignas(16) unsigned short Ks[2][64 * 64];
  __shared__ alignas(16) unsigned short Vs[2][64 * 64];
  const int bid = blockIdx.x;
  const int qt = bid >> 6;
  const int bh = bid & 63;
  const int b = bh >> 4, h = bh & 15;
  const int t = threadIdx.x, l = t & 63, w = t >> 6;
  const int lr = l & 15, lg = l >> 4;
  const long rowbase = (long)b * 2048;
  const int colbase = h * 64;
  const int q0 = qt * 64 + w * 16;
  const int q1 = (31 - qt) * 64 + w * 16;
  const int q0row = q0 + lr, q1row = q1 + lr;
  const int nkv = 32 - qt;

  bf16x8 qf[2][2];
#pragma unroll
  for (int c = 0; c < 2; ++c) {
    qf[0][c] = *(const bf16x8*)(Qp + (rowbase + q0 + lr) * 1024 + colbase + c * 32 + lg * 8);
    qf[1][c] = *(const bf16x8*)(Qp + (rowbase + q1 + lr) * 1024 + colbase + c * 32 + lg * 8);
  }

  f32x4 cacc[2][4];
  float l_r[2];
#pragma unroll
  for (int s = 0; s < 2; ++s) {
    l_r[s] = 0.f;
#pragma unroll
    for (int n = 0; n < 4; ++n) cacc[s][n] = f32x4{0.f, 0.f, 0.f, 0.f};
  }

  const int srow = w * 16 + (l >> 3);
  const int scol = (l & 7) * 8;
  const int kswz = scol ^ ((srow & 7) << 3);
  const unsigned short* kp = Kp + (rowbase + srow) * 1024 + colbase + kswz;
  const unsigned short* vp = Vt + ((long)(bh * 64 + srow)) * 2048 + kswz;
  unsigned short* ksd0 = &Ks[0][(w * 16) * 64];
  unsigned short* vsd0 = &Vs[0][(w * 16) * 64];

#define STAGE(buf)                                    \
  do {                                                \
    gload16(kp, ksd0 + (buf) * 4096);                 \
    gload16(kp + 8 * 1024, ksd0 + (buf) * 4096 + 512);\
    gload16(vp, vsd0 + (buf) * 4096);                 \
    gload16(vp + 8 * 2048, vsd0 + (buf) * 4096 + 512);\
    kp += 64 * 1024;                                  \
    vp += 64;                                         \
  } while (0)

#define TILE_WAIT(j)                                                          \
  do {                                                                        \
    if ((j) == nkv - 1) asm volatile("s_waitcnt vmcnt(0)" ::: "memory");      \
    else                asm volatile("s_waitcnt vmcnt(4)" ::: "memory");      \
    asm volatile("s_barrier" ::: "memory");                                   \
  } while (0)

  STAGE(0);
  STAGE(1);

  int j = 0;
  for (; j <= qt; ++j) {  // both strips active
    const int cur = j & 1;
    TILE_WAIT(j);
    attn_tile<1>(Ks[cur], Vs[cur], lr, lg, j == qt, false, j * 64, q0row, q1row,
                 qf, cacc, l_r);
    asm volatile("s_barrier" ::: "memory");
    if (j + 2 < nkv) STAGE(cur);
  }
  for (; j < nkv; ++j) {  // long strip only
    const int cur = j & 1;
    TILE_WAIT(j);
    attn_tile<0>(Ks[cur], Vs[cur], lr, lg, false, j == nkv - 1, j * 64, q0row, q1row,
                 qf, cacc, l_r);
    asm volatile("s_barrier" ::: "memory");
    if (j + 2 < nkv) STAGE(cur);
  }
#undef STAGE
#undef TILE_WAIT

#pragma unroll
  for (int s = 0; s < 2; ++s) {
    float rs = l_r[s];
    rs += __shfl_xor(rs, 16);
    rs += __shfl_xor(rs, 32);
    float invl = 1.f / rs;
    float ilq[4];
#pragma unroll
    for (int r = 0; r < 4; ++r) ilq[r] = __shfl(invl, lg * 20 + r);
    const int qs = (s == 0) ? q0 : q1;
#pragma unroll
    for (int n = 0; n < 4; ++n)
#pragma unroll
      for (int r = 0; r < 4; ++r) {
        long row = rowbase + qs + lg * 4 + r;
        Ctx[row * 1024 + colbase + n * 16 + lr] = f2bf(cacc[s][n][r] * ilq[r]);
      }
  }
}

extern "C" void kernel_launch(void* const* d_in, const int* in_sizes, int n_in,
                              void* d_out, int out_size, void* d_ws, size_t ws_size,
                              hipStream_t stream) {
  (void)in_sizes; (void)n_in; (void)out_size; (void)ws_size;
  const float* x  = (const float*)d_in[0];
  const float* Wq = (const float*)d_in[1];
  const float* Wk = (const float*)d_in[2];
  const float* Wv = (const float*)d_in[3];
  const float* Wo = (const float*)d_in[4];
  const float* bo = (const float*)d_in[5];
  float* out = (float*)d_out;

  unsigned short* ws = (unsigned short*)d_ws;
  unsigned short* xb  = ws;                       // 8192*1024 bf16
  unsigned short* WqT = ws + 8388608;             // 4x 1024*1024 (Wq,Wk,Wv,Wo)
  unsigned short* WoT = WqT + 3145728;
  unsigned short* QKV = WqT + 4194304;            // 3 planes: Q | K | V^T (8M each)
  unsigned short* Qp  = QKV;
  unsigned short* Kp  = QKV + 8388608;
  unsigned short* Vt  = QKV + 16777216;
  unsigned short* Ctx = QKV + 25165824;           // 8192*1024

  // fused x->bf16 + 4x weight transpose (one launch)
  prep<<<6144, 256, 0, stream>>>(x, xb, Wq, Wk, Wv, Wo, WqT);

  // fused QKV projection: M=8192, N=3072, K=1024 (128x128 tiles, 1536 blocks
  // = 3 exact rounds at 2 blocks/CU); Q/K planes + V^T scatter in epilogue.
  gemm97<0><<<1536, 256, 0, stream>>>(xb, WqT, QKV, nullptr, nullptr,
                                      8192, 3072, 1024);

  // flash attention: 64 bh x 16 paired-strip blocks
  flash_attn<<<1024, 256, 0, stream>>>(Qp, Kp, Vt, Ctx);

  // output projection + bias: fp32 out (128x128 tiles, 512 blocks = 1 round)
  gemm97<1><<<512, 256, 0, stream>>>(Ctx, WoT, nullptr, out, bo,
                                     8192, 1024, 1024);
}

// Round 16
// 148.287 us; speedup vs baseline: 1.0001x; 1.0001x over previous
//
#include <hip/hip_runtime.h>

typedef __attribute__((ext_vector_type(8))) short bf16x8;
typedef __attribute__((ext_vector_type(4))) float f32x4;
typedef __attribute__((ext_vector_type(4))) unsigned uint4v;

#define SM_C 0.18033688011112042f  // 0.125 * log2(e)
#define SM_M 20.0f                 // static softmax shift (exact; f32 overflow needs s>730)
#define MFMA16 __builtin_amdgcn_mfma_f32_16x16x32_bf16

__device__ __forceinline__ unsigned short f2bf(float f) {
  unsigned u = __builtin_bit_cast(unsigned, f);
  u += 0x7fffu + ((u >> 16) & 1u);
  return (unsigned short)(u >> 16);
}

__device__ __forceinline__ unsigned cvtpk(float lo, float hi) {
  unsigned r;
  asm volatile("v_cvt_pk_bf16_f32 %0, %1, %2" : "=v"(r) : "v"(lo), "v"(hi));
  return r;
}

__device__ __forceinline__ void gload16(const void* g, void* lds) {
  __builtin_amdgcn_global_load_lds(
      (const __attribute__((address_space(1))) void*)g,
      (__attribute__((address_space(3))) void*)lds, 16, 0, 0);
}

#define BARRIER __builtin_amdgcn_s_barrier()
#define LGKM0 asm volatile("s_waitcnt lgkmcnt(0)" ::: "memory")
#define VM0 asm volatile("s_waitcnt vmcnt(0)" ::: "memory")

// ---------------- prep: x->bf16 (blocks 0..2047) + 4x W transpose ----------
__global__ __launch_bounds__(256) void prep(const float* __restrict__ x,
                                            unsigned short* __restrict__ xb,
                                            const float* __restrict__ W0,
                                            const float* __restrict__ W1,
                                            const float* __restrict__ W2,
                                            const float* __restrict__ W3,
                                            unsigned short* __restrict__ WT) {
  __shared__ float tile[32][33];
  const int bid = blockIdx.x;
  if (bid < 2048) {
    int i = bid * 256 + threadIdx.x;
    for (; i < 2097152; i += 2048 * 256) {
      float4 v = ((const float4*)x)[i];
      unsigned long long packed = (unsigned long long)f2bf(v.x) |
                                  ((unsigned long long)f2bf(v.y) << 16) |
                                  ((unsigned long long)f2bf(v.z) << 32) |
                                  ((unsigned long long)f2bf(v.w) << 48);
      ((unsigned long long*)xb)[i] = packed;
    }
  } else {
    int b2 = bid - 2048;
    const int z = b2 >> 10;
    b2 &= 1023;
    const int bx = b2 & 31, by = b2 >> 5;
    const float* W = (z == 0) ? W0 : (z == 1) ? W1 : (z == 2) ? W2 : W3;
    unsigned short* WTo = WT + (size_t)z * 1048576;
    const int tx = threadIdx.x & 31, ty = threadIdx.x >> 5;
    const int xcol = bx * 32 + tx;
    for (int i = 0; i < 4; ++i) {
      int r = ty + i * 8;
      tile[r][tx] = W[(by * 32 + r) * 1024 + xcol];
    }
    __syncthreads();
    const int nx = by * 32 + tx;
    for (int i = 0; i < 4; ++i) {
      int r = ty + i * 8;
      WTo[(long)(bx * 32 + r) * 1024 + nx] = f2bf(tile[tx][r]);
    }
  }
}

// ---------------- GEMM (m97-style, 128x128, BK=64, 2 blocks/CU) -------------
// C[M][N] = A[M][K] * BT[N][K]^T.  256 thr = 4 waves (2M x 2N), wave 64x64.
// Per K-tile: STAGE(t+1) -> 16 ds_read_b128 -> lgkm0 -> 32 MFMA (setprio)
// -> vmcnt(0) -> ONE barrier.  Hazards: stage into buf^1 is safe because all
// waves' reads of buf^1 (tile t-1) completed via their lgkm0 before tile t's
// entry barrier; next tile's reads of buf^1 are gated by vmcnt(0)+barrier.
// LDS 64KB/block -> 2 independent blocks/CU (inter-block overlap, m114).
// MODE 0: Q/K plane stores or V^T key-permuted scatter (routed per tn).
// MODE 1: f32 + bias.
template <int MODE>
__global__ __launch_bounds__(256) void gemm97(const unsigned short* __restrict__ A,
                                              const unsigned short* __restrict__ BT,
                                              unsigned short* __restrict__ Cb,
                                              float* __restrict__ Cf,
                                              const float* __restrict__ bias,
                                              int M, int N, int K) {
  __shared__ alignas(16) unsigned short As[2][128 * 64];
  __shared__ alignas(16) unsigned short Bs[2][128 * 64];

  const int nbn = N >> 7;
  const int tmg = (M >> 7) >> 3;   // tiles per XCD row-group
  const int cc = blockIdx.x >> 3, xc = blockIdx.x & 7;
  const int tm = xc * tmg + cc / nbn, tn = cc % nbn;

  const int t = threadIdx.x, l = t & 63, wid = t >> 6;
  const int wm = wid >> 1, wn = wid & 1;
  const int lr = l & 15, lg = l >> 4;

  f32x4 acc[4][4] = {};

  // staging: thread t covers (row q*32+sq, slot t&7); source pre-swizzled
  // (slot ^ row&7), LDS dest linear (rule 21).  row&7 == sq&7.
  const int sq = t >> 3;           // 0..31
  const int sslot8 = ((t & 7) ^ (sq & 7)) * 8;
  const unsigned short* Ath = A + ((long)tm * 128 + sq) * K + sslot8;
  const unsigned short* Bth = BT + ((long)tn * 128 + sq) * K + sslot8;
  const int ldsoff = sq * 64 + (t & 7) * 8;

#define STG(buf, kt)                                                      \
  do {                                                                    \
    _Pragma("unroll") for (int q_ = 0; q_ < 4; ++q_) {                    \
      gload16(Ath + (long)(q_ * 32) * K + (kt) * 64,                      \
              &As[buf][q_ * 2048 + ldsoff]);                              \
      gload16(Bth + (long)(q_ * 32) * K + (kt) * 64,                      \
              &Bs[buf][q_ * 2048 + ldsoff]);                              \
    }                                                                     \
  } while (0)

  const int NT = K >> 6;
  STG(0, 0);
  VM0;
  BARRIER;

  const int offk0 = (lg ^ (lr & 7)) * 8;
  const int offk1 = ((4 + lg) ^ (lr & 7)) * 8;
  const int arow0 = (wm * 64 + lr) * 64;
  const int brow0 = (wn * 64 + lr) * 64;

  for (int tt = 0; tt < NT; ++tt) {
    const int cur = tt & 1;
    if (tt + 1 < NT) STG(cur ^ 1, tt + 1);

    const unsigned short* Ac = As[cur];
    const unsigned short* Bc = Bs[cur];
    bf16x8 af[4][2], bfr[4][2];
#pragma unroll
    for (int m = 0; m < 4; ++m) {
      const unsigned short* ap = Ac + arow0 + m * 1024;
      af[m][0] = *(const bf16x8*)(ap + offk0);
      af[m][1] = *(const bf16x8*)(ap + offk1);
    }
#pragma unroll
    for (int n = 0; n < 4; ++n) {
      const unsigned short* bp = Bc + brow0 + n * 1024;
      bfr[n][0] = *(const bf16x8*)(bp + offk0);
      bfr[n][1] = *(const bf16x8*)(bp + offk1);
    }
    LGKM0;
    __builtin_amdgcn_s_setprio(1);
#pragma unroll
    for (int m = 0; m < 4; ++m)
#pragma unroll
      for (int n = 0; n < 4; ++n) {
        acc[m][n] = MFMA16(af[m][0], bfr[n][0], acc[m][n], 0, 0, 0);
        acc[m][n] = MFMA16(af[m][1], bfr[n][1], acc[m][n], 0, 0, 0);
      }
    __builtin_amdgcn_s_setprio(0);

    if (tt + 1 < NT) {
      VM0;      // tile t+1's stages landed (cheap: issued before ds+MFMA)
      BARRIER;  // all waves' reads of buf[cur] also done (each via lgkm0)
    }
  }
#undef STG

  const long crow = (long)tm * 128 + wm * 64;
  const int ccolw = wn * 64;

  if constexpr (MODE == 1) {
#pragma unroll
    for (int m = 0; m < 4; ++m)
#pragma unroll
      for (int n = 0; n < 4; ++n)
#pragma unroll
        for (int r = 0; r < 4; ++r) {
          long row = crow + m * 16 + lg * 4 + r;
          int col = tn * 128 + ccolw + n * 16 + lr;
          Cf[row * N + col] = acc[m][n][r] + bias[col];
        }
  } else {
    if (tn < 16) {
      // Q plane (tn 0-7) or K plane (tn 8-15), stride 1024
      unsigned short* pl = Cb + ((tn < 8) ? 0 : 8388608);
      const int pc = (tn & 7) * 128 + ccolw + lr;
#pragma unroll
      for (int m = 0; m < 4; ++m)
#pragma unroll
        for (int n = 0; n < 4; ++n)
#pragma unroll
          for (int r = 0; r < 4; ++r) {
            long row = crow + m * 16 + lg * 4 + r;
            pl[row * 1024 + pc + n * 16] = f2bf(acc[m][n][r]);
          }
    } else {
      // V^T plane, key permutation: Vt[(b*16+h)*64+hd][2048 s-perm]
      unsigned short* VtW = Cb + 16777216;
      const int bq = (tm >> 4) << 4;                 // b*16
      const int sbase = ((tm & 15) << 7) + wm * 64;  // s within batch
#pragma unroll
      for (int m = 0; m < 4; ++m) {
        const int srow_ = sbase + m * 16 + lg * 4;
        const int lwb = srow_ & 63;
        const int stt = srow_ >> 6;
        const int vp0 = (lwb & 32) | (((lwb >> 2) & 3) << 3) | (((lwb >> 4) & 1) << 2);
#pragma unroll
        for (int n = 0; n < 4; ++n) {
          const int vcol = (tn - 16) * 128 + ccolw + n * 16 + lr;
          const long vtrow = (long)(bq + (vcol >> 6)) * 64 + (vcol & 63);
          unsigned long long pk4 =
              (unsigned long long)f2bf(acc[m][n][0]) |
              ((unsigned long long)f2bf(acc[m][n][1]) << 16) |
              ((unsigned long long)f2bf(acc[m][n][2]) << 32) |
              ((unsigned long long)f2bf(acc[m][n][3]) << 48);
          *(unsigned long long*)(VtW + vtrow * 2048 + stt * 64 + vp0) = pk4;
        }
      }
    }
  }
}

// ---------------- Flash attention tile body (static-max, scalar accum) ------
template <int TWO>
__device__ __forceinline__ void attn_tile(
    const unsigned short* __restrict__ Kc, const unsigned short* __restrict__ Vc,
    int lr, int lg, bool mask0, bool mask1, int kv0, int q0row, int q1row,
    const bf16x8 (&qf)[2][2], f32x4 (&cacc)[2][4], float (&l_r)[2]) {
  constexpr int S0 = TWO ? 0 : 1;
  f32x4 p[2][4];
#pragma unroll
  for (int s = S0; s < 2; ++s)
#pragma unroll
    for (int g = 0; g < 4; ++g) p[s][g] = f32x4{0.f, 0.f, 0.f, 0.f};

  __builtin_amdgcn_s_setprio(1);
#pragma unroll
  for (int g = 0; g < 4; ++g) {
    const int key = g * 16 + lr;
    const int swz = (key & 7) << 3;
#pragma unroll
    for (int c = 0; c < 2; ++c) {
      bf16x8 kf = *(const bf16x8*)(Kc + key * 64 + ((c * 32 + lg * 8) ^ swz));
#pragma unroll
      for (int s = S0; s < 2; ++s)
        p[s][g] = MFMA16(kf, qf[s][c], p[s][g], 0, 0, 0);
    }
  }
  __builtin_amdgcn_s_setprio(0);

  if (TWO && mask0) {
#pragma unroll
    for (int g = 0; g < 4; ++g)
#pragma unroll
      for (int r = 0; r < 4; ++r)
        if (kv0 + g * 16 + lg * 4 + r > q0row) p[0][g][r] = -1e30f;
  }
  if (mask1) {
#pragma unroll
    for (int g = 0; g < 4; ++g)
#pragma unroll
      for (int r = 0; r < 4; ++r)
        if (kv0 + g * 16 + lg * 4 + r > q1row) p[1][g][r] = -1e30f;
  }

  const float SM_NMC = -SM_M * SM_C;
  unsigned pk[2][4][2];
#pragma unroll
  for (int s = S0; s < 2; ++s) {
    float e[4][4];
#pragma unroll
    for (int g = 0; g < 4; ++g)
#pragma unroll
      for (int r = 0; r < 4; ++r)
        e[g][r] = __builtin_amdgcn_exp2f(__builtin_fmaf(p[s][g][r], SM_C, SM_NMC));
    float t0 = (e[0][0] + e[0][1]) + (e[0][2] + e[0][3]);
    float t1 = (e[1][0] + e[1][1]) + (e[1][2] + e[1][3]);
    float t2 = (e[2][0] + e[2][1]) + (e[2][2] + e[2][3]);
    float t3 = (e[3][0] + e[3][1]) + (e[3][2] + e[3][3]);
    l_r[s] += (t0 + t1) + (t2 + t3);
#pragma unroll
    for (int g = 0; g < 4; ++g) {
      pk[s][g][0] = cvtpk(e[g][0], e[g][1]);
      pk[s][g][1] = cvtpk(e[g][2], e[g][3]);
    }
  }

#pragma unroll
  for (int sl = 0; sl < 2; ++sl) {
    bf16x8 vf[4];
#pragma unroll
    for (int n = 0; n < 4; ++n) {
      const int hd = n * 16 + lr;
      vf[n] = *(const bf16x8*)(Vc + hd * 64 + ((sl * 32 + lg * 8) ^ ((hd & 7) << 3)));
    }
    __builtin_amdgcn_s_setprio(1);
#pragma unroll
    for (int s = S0; s < 2; ++s) {
      uint4v pw = {pk[s][2 * sl][0], pk[s][2 * sl][1], pk[s][2 * sl + 1][0], pk[s][2 * sl + 1][1]};
      bf16x8 pa = __builtin_bit_cast(bf16x8, pw);
#pragma unroll
      for (int n = 0; n < 4; ++n)
        cacc[s][n] = MFMA16(pa, vf[n], cacc[s][n], 0, 0, 0);
    }
    __builtin_amdgcn_s_setprio(0);
  }
}

// ---------------- Flash attention (paired strips, counted-vmcnt pipeline) ---
__global__ __launch_bounds__(256, 4) void flash_attn(const unsigned short* __restrict__ Qp,
                                                     const unsigned short* __restrict__ Kp,
                                                     const unsigned short* __restrict__ Vt,
                                                     unsigned short* __restrict__ Ctx) {
  __shared__ alignas(16) unsigned short Ks[2][64 * 64];
  __shared__ alignas(16) unsigned short Vs[2][64 * 64];
  const int bid = blockIdx.x;
  const int qt = bid >> 6;
  const int bh = bid & 63;
  const int b = bh >> 4, h = bh & 15;
  const int t = threadIdx.x, l = t & 63, w = t >> 6;
  const int lr = l & 15, lg = l >> 4;
  const long rowbase = (long)b * 2048;
  const int colbase = h * 64;
  const int q0 = qt * 64 + w * 16;
  const int q1 = (31 - qt) * 64 + w * 16;
  const int q0row = q0 + lr, q1row = q1 + lr;
  const int nkv = 32 - qt;

  bf16x8 qf[2][2];
#pragma unroll
  for (int c = 0; c < 2; ++c) {
    qf[0][c] = *(const bf16x8*)(Qp + (rowbase + q0 + lr) * 1024 + colbase + c * 32 + lg * 8);
    qf[1][c] = *(const bf16x8*)(Qp + (rowbase + q1 + lr) * 1024 + colbase + c * 32 + lg * 8);
  }

  f32x4 cacc[2][4];
  float l_r[2];
#pragma unroll
  for (int s = 0; s < 2; ++s) {
    l_r[s] = 0.f;
#pragma unroll
    for (int n = 0; n < 4; ++n) cacc[s][n] = f32x4{0.f, 0.f, 0.f, 0.f};
  }

  const int srow = w * 16 + (l >> 3);
  const int scol = (l & 7) * 8;
  const int kswz = scol ^ ((srow & 7) << 3);
  const unsigned short* kp = Kp + (rowbase + srow) * 1024 + colbase + kswz;
  const unsigned short* vp = Vt + ((long)(bh * 64 + srow)) * 2048 + kswz;
  unsigned short* ksd0 = &Ks[0][(w * 16) * 64];
  unsigned short* vsd0 = &Vs[0][(w * 16) * 64];

#define STAGE(buf)                                    \
  do {                                                \
    gload16(kp, ksd0 + (buf) * 4096);                 \
    gload16(kp + 8 * 1024, ksd0 + (buf) * 4096 + 512);\
    gload16(vp, vsd0 + (buf) * 4096);                 \
    gload16(vp + 8 * 2048, vsd0 + (buf) * 4096 + 512);\
    kp += 64 * 1024;                                  \
    vp += 64;                                         \
  } while (0)

#define TILE_WAIT(j)                                                          \
  do {                                                                        \
    if ((j) == nkv - 1) asm volatile("s_waitcnt vmcnt(0)" ::: "memory");      \
    else                asm volatile("s_waitcnt vmcnt(4)" ::: "memory");      \
    asm volatile("s_barrier" ::: "memory");                                   \
  } while (0)

  STAGE(0);
  STAGE(1);

  int j = 0;
  for (; j <= qt; ++j) {  // both strips active
    const int cur = j & 1;
    TILE_WAIT(j);
    attn_tile<1>(Ks[cur], Vs[cur], lr, lg, j == qt, false, j * 64, q0row, q1row,
                 qf, cacc, l_r);
    asm volatile("s_barrier" ::: "memory");
    if (j + 2 < nkv) STAGE(cur);
  }
  for (; j < nkv; ++j) {  // long strip only
    const int cur = j & 1;
    TILE_WAIT(j);
    attn_tile<0>(Ks[cur], Vs[cur], lr, lg, false, j == nkv - 1, j * 64, q0row, q1row,
                 qf, cacc, l_r);
    asm volatile("s_barrier" ::: "memory");
    if (j + 2 < nkv) STAGE(cur);
  }
#undef STAGE
#undef TILE_WAIT

#pragma unroll
  for (int s = 0; s < 2; ++s) {
    float rs = l_r[s];
    rs += __shfl_xor(rs, 16);
    rs += __shfl_xor(rs, 32);
    float invl = 1.f / rs;
    float ilq[4];
#pragma unroll
    for (int r = 0; r < 4; ++r) ilq[r] = __shfl(invl, lg * 20 + r);
    const int qs = (s == 0) ? q0 : q1;
#pragma unroll
    for (int n = 0; n < 4; ++n)
#pragma unroll
      for (int r = 0; r < 4; ++r) {
        long row = rowbase + qs + lg * 4 + r;
        Ctx[row * 1024 + colbase + n * 16 + lr] = f2bf(cacc[s][n][r] * ilq[r]);
      }
  }
}

extern "C" void kernel_launch(void* const* d_in, const int* in_sizes, int n_in,
                              void* d_out, int out_size, void* d_ws, size_t ws_size,
                              hipStream_t stream) {
  (void)in_sizes; (void)n_in; (void)out_size; (void)ws_size;
  const float* x  = (const float*)d_in[0];
  const float* Wq = (const float*)d_in[1];
  const float* Wk = (const float*)d_in[2];
  const float* Wv = (const float*)d_in[3];
  const float* Wo = (const float*)d_in[4];
  const float* bo = (const float*)d_in[5];
  float* out = (float*)d_out;

  unsigned short* ws = (unsigned short*)d_ws;
  unsigned short* xb  = ws;                       // 8192*1024 bf16
  unsigned short* WqT = ws + 8388608;             // 4x 1024*1024 (Wq,Wk,Wv,Wo)
  unsigned short* WoT = WqT + 3145728;
  unsigned short* QKV = WqT + 4194304;            // 3 planes: Q | K | V^T (8M each)
  unsigned short* Qp  = QKV;
  unsigned short* Kp  = QKV + 8388608;
  unsigned short* Vt  = QKV + 16777216;
  unsigned short* Ctx = QKV + 25165824;           // 8192*1024

  // fused x->bf16 + 4x weight transpose (one launch)
  prep<<<6144, 256, 0, stream>>>(x, xb, Wq, Wk, Wv, Wo, WqT);

  // fused QKV projection: M=8192, N=3072, K=1024 (128x128 tiles, 1536 blocks
  // = 3 exact rounds at 2 blocks/CU); Q/K planes + V^T scatter in epilogue.
  gemm97<0><<<1536, 256, 0, stream>>>(xb, WqT, QKV, nullptr, nullptr,
                                      8192, 3072, 1024);

  // flash attention: 64 bh x 16 paired-strip blocks
  flash_attn<<<1024, 256, 0, stream>>>(Qp, Kp, Vt, Ctx);

  // output projection + bias: fp32 out (128x128 tiles, 512 blocks = 1 round)
  gemm97<1><<<512, 256, 0, stream>>>(Ctx, WoT, nullptr, out, bo,
                                     8192, 1024, 1024);
}

// Round 17
// 135.589 us; speedup vs baseline: 1.0938x; 1.0936x over previous
//
#include <hip/hip_runtime.h>

typedef __attribute__((ext_vector_type(8))) short bf16x8;
typedef __attribute__((ext_vector_type(4))) float f32x4;
typedef __attribute__((ext_vector_type(4))) unsigned uint4v;

#define SM_C 0.18033688011112042f  // 0.125 * log2(e)
#define SM_M 20.0f                 // static softmax shift (exact; f32 overflow needs s>730)
#define MFMA16 __builtin_amdgcn_mfma_f32_16x16x32_bf16

__device__ __forceinline__ unsigned short f2bf(float f) {
  unsigned u = __builtin_bit_cast(unsigned, f);
  u += 0x7fffu + ((u >> 16) & 1u);
  return (unsigned short)(u >> 16);
}

__device__ __forceinline__ unsigned cvtpk(float lo, float hi) {
  unsigned r;
  asm volatile("v_cvt_pk_bf16_f32 %0, %1, %2" : "=v"(r) : "v"(lo), "v"(hi));
  return r;
}

__device__ __forceinline__ void gload16(const void* g, void* lds) {
  __builtin_amdgcn_global_load_lds(
      (const __attribute__((address_space(1))) void*)g,
      (__attribute__((address_space(3))) void*)lds, 16, 0, 0);
}

#define BARRIER __builtin_amdgcn_s_barrier()
#define LGKM0 asm volatile("s_waitcnt lgkmcnt(0)" ::: "memory")

// ---------------- prep: x->bf16 (blocks 0..2047) + 4x W transpose ----------
__global__ __launch_bounds__(256) void prep(const float* __restrict__ x,
                                            unsigned short* __restrict__ xb,
                                            const float* __restrict__ W0,
                                            const float* __restrict__ W1,
                                            const float* __restrict__ W2,
                                            const float* __restrict__ W3,
                                            unsigned short* __restrict__ WT) {
  __shared__ float tile[32][33];
  const int bid = blockIdx.x;
  if (bid < 2048) {
    int i = bid * 256 + threadIdx.x;
    for (; i < 2097152; i += 2048 * 256) {
      float4 v = ((const float4*)x)[i];
      unsigned long long packed = (unsigned long long)f2bf(v.x) |
                                  ((unsigned long long)f2bf(v.y) << 16) |
                                  ((unsigned long long)f2bf(v.z) << 32) |
                                  ((unsigned long long)f2bf(v.w) << 48);
      ((unsigned long long*)xb)[i] = packed;
    }
  } else {
    int b2 = bid - 2048;
    const int z = b2 >> 10;
    b2 &= 1023;
    const int bx = b2 & 31, by = b2 >> 5;
    const float* W = (z == 0) ? W0 : (z == 1) ? W1 : (z == 2) ? W2 : W3;
    unsigned short* WTo = WT + (size_t)z * 1048576;
    const int tx = threadIdx.x & 31, ty = threadIdx.x >> 5;
    const int xcol = bx * 32 + tx;
    for (int i = 0; i < 4; ++i) {
      int r = ty + i * 8;
      tile[r][tx] = W[(by * 32 + r) * 1024 + xcol];
    }
    __syncthreads();
    const int nx = by * 32 + tx;
    for (int i = 0; i < 4; ++i) {
      int r = ty + i * 8;
      WTo[(long)(bx * 32 + r) * 1024 + nx] = f2bf(tile[tx][r]);
    }
  }
}

// ---------------- GEMM: A triple-buffer, B double-buffer, 1 vmcnt/K-tile ----
// (R14-proven structure.)  MODE 0: split-plane output routed per 16-col group
// (Q plane / K plane / V^T key-permuted packed-8B scatter).  MODE 1: f32+bias.
template <int NR, int MODE>
__global__ __launch_bounds__(512, 1) void gemm3b(const unsigned short* __restrict__ A,
                                                 const unsigned short* __restrict__ BT,
                                                 unsigned short* __restrict__ Cb,
                                                 float* __restrict__ Cf,
                                                 const float* __restrict__ bias,
                                                 int M, int N, int K) {
  constexpr int BN = NR * 64;
  __shared__ alignas(16) unsigned short As[3][256 * 64];
  __shared__ alignas(16) unsigned short Bs[2][BN * 64];

  const int nbn = N / BN;
  const int tmg = (M / 256) / 8;
  const int cc = blockIdx.x >> 3, xc = blockIdx.x & 7;
  const int tm = xc * tmg + cc / nbn, tn = cc % nbn;

  const int t = threadIdx.x, l = t & 63, wid = t >> 6;
  const int wm = wid >> 2, wn = wid & 3;
  const int lr = l & 15, lg = l >> 4;

  f32x4 acc[8][NR] = {};

  const int sq = t >> 3;
  const int sslot8 = ((t & 7) ^ (sq & 7)) * 8;
  const unsigned short* Ath = A + ((long)tm * 256 + sq) * K + sslot8;
  const unsigned short* Bth = BT + ((long)tn * BN + sq) * K + sslot8;
  const int ldsoff = sq * 64 + (t & 7) * 8;

#define STGA(buf, q, kt) \
  gload16(Ath + (long)((q)*64) * K + (kt)*64, &As[buf][(q)*4096 + ldsoff])
#define STGB(buf, u, kt) \
  gload16(Bth + (long)((u)*64) * K + (kt)*64, &Bs[buf][(u)*4096 + ldsoff])

  const int NT = K >> 6;
#pragma unroll
  for (int q = 0; q < 4; ++q) STGA(0, q, 0);
#pragma unroll
  for (int u = 0; u < NR; ++u) STGB(0, u, 0);
#pragma unroll
  for (int q = 0; q < 4; ++q) STGA(1, q, 1);

  const int offk0 = (lg ^ (lr & 7)) * 8;
  const int offk1 = ((4 + lg) ^ (lr & 7)) * 8;
  const int arow0 = (wm * 128 + lr) * 64;
  const int brow0 = (wn * (NR * 16) + lr) * 64;

#define DS_A(MH)                                                   \
  _Pragma("unroll") for (int m_ = 0; m_ < 4; ++m_) {               \
    const unsigned short* ap_ = Ac + arow0 + ((MH)*4 + m_) * 1024; \
    af[m_][0] = *(const bf16x8*)(ap_ + offk0);                     \
    af[m_][1] = *(const bf16x8*)(ap_ + offk1);                     \
  }
#define DS_B_ALL                                          \
  _Pragma("unroll") for (int n_ = 0; n_ < NR; ++n_) {     \
    const unsigned short* bp_ = Bc + brow0 + n_ * 1024;   \
    bfr[n_][0] = *(const bf16x8*)(bp_ + offk0);           \
    bfr[n_][1] = *(const bf16x8*)(bp_ + offk1);           \
  }
#define MM(MH)                                                              \
  __builtin_amdgcn_s_setprio(1);                                            \
  _Pragma("unroll") for (int m_ = 0; m_ < 4; ++m_)                          \
  _Pragma("unroll") for (int n_ = 0; n_ < NR; ++n_) {                       \
    acc[(MH)*4 + m_][n_] = MFMA16(af[m_][0], bfr[n_][0],                    \
                                  acc[(MH)*4 + m_][n_], 0, 0, 0);           \
    acc[(MH)*4 + m_][n_] = MFMA16(af[m_][1], bfr[n_][1],                    \
                                  acc[(MH)*4 + m_][n_], 0, 0, 0);           \
  }                                                                         \
  __builtin_amdgcn_s_setprio(0);

  int cur3 = 0;
  int stg3 = 2;
  for (int tt = 0; tt < NT; ++tt) {
    const unsigned short* Ac = As[cur3];
    const unsigned short* Bc = Bs[tt & 1];

    bf16x8 af[4][2];
    bf16x8 bfr[NR][2];

    if (tt == NT - 1) asm volatile("s_waitcnt vmcnt(0)" ::: "memory");
    else              asm volatile("s_waitcnt vmcnt(4)" ::: "memory");
    BARRIER;
    DS_A(0);
    DS_B_ALL;
    if (tt + 1 < NT) {
      const int nbB = (tt + 1) & 1;
#pragma unroll
      for (int u = 0; u < NR; ++u) STGB(nbB, u, tt + 1);
    }
    BARRIER;
    LGKM0;
    MM(0);

    DS_A(1);
    if (tt + 2 < NT) {
#pragma unroll
      for (int q = 0; q < 4; ++q) STGA(stg3, q, tt + 2);
    }
    BARRIER;
    LGKM0;
    MM(1);

    cur3 = (cur3 == 2) ? 0 : cur3 + 1;
    stg3 = (stg3 == 2) ? 0 : stg3 + 1;
  }
#undef DS_A
#undef DS_B_ALL
#undef MM
#undef STGA
#undef STGB

  const long crow = (long)tm * 256 + wm * 128;
  const int ccol = tn * BN + wn * (NR * 16);

  if constexpr (MODE == 1) {
#pragma unroll
    for (int m = 0; m < 8; ++m)
#pragma unroll
      for (int n = 0; n < NR; ++n)
#pragma unroll
        for (int r = 0; r < 4; ++r) {
          long row = crow + m * 16 + lg * 4 + r;
          int col = ccol + n * 16 + lr;
          Cf[row * N + col] = acc[m][n][r] + bias[col];
        }
  } else {
#pragma unroll
    for (int n = 0; n < NR; ++n) {
      const int colg = ccol + n * 16;  // wave-uniform
      const int plane = colg >> 10;
      if (plane < 2) {
        unsigned short* pl = Cb + (size_t)plane * 8388608;
        const int pc = (colg & 1023) + lr;
#pragma unroll
        for (int m = 0; m < 8; ++m)
#pragma unroll
          for (int r = 0; r < 4; ++r) {
            long row = crow + m * 16 + lg * 4 + r;
            pl[row * 1024 + pc] = f2bf(acc[m][n][r]);
          }
      } else {
        unsigned short* VtW = Cb + 16777216;
        const int bq = (tm >> 3) << 4;
        const int sbase = ((tm & 7) << 8) + wm * 128;
        const int vcol = (colg & 1023) + lr;
        const long vtrow = (long)(bq + (vcol >> 6)) * 64 + (vcol & 63);
#pragma unroll
        for (int m = 0; m < 8; ++m) {
          const int srow_ = sbase + m * 16 + lg * 4;
          const int lwb = srow_ & 63;
          const int stt = srow_ >> 6;
          const int vp0 = (lwb & 32) | (((lwb >> 2) & 3) << 3) | (((lwb >> 4) & 1) << 2);
          unsigned long long pk4 =
              (unsigned long long)f2bf(acc[m][n][0]) |
              ((unsigned long long)f2bf(acc[m][n][1]) << 16) |
              ((unsigned long long)f2bf(acc[m][n][2]) << 32) |
              ((unsigned long long)f2bf(acc[m][n][3]) << 48);
          *(unsigned long long*)(VtW + vtrow * 2048 + stt * 64 + vp0) = pk4;
        }
      }
    }
  }
}

// ---------------- Flash attention tile body (static-max, scalar accum) ------
template <int TWO>
__device__ __forceinline__ void attn_tile(
    const unsigned short* __restrict__ Kc, const unsigned short* __restrict__ Vc,
    int lr, int lg, bool mask0, bool mask1, int kv0, int q0row, int q1row,
    const bf16x8 (&qf)[2][2], f32x4 (&cacc)[2][4], float (&l_r)[2]) {
  constexpr int S0 = TWO ? 0 : 1;
  f32x4 p[2][4];
#pragma unroll
  for (int s = S0; s < 2; ++s)
#pragma unroll
    for (int g = 0; g < 4; ++g) p[s][g] = f32x4{0.f, 0.f, 0.f, 0.f};

  __builtin_amdgcn_s_setprio(1);
#pragma unroll
  for (int g = 0; g < 4; ++g) {
    const int key = g * 16 + lr;
    const int swz = (key & 7) << 3;
#pragma unroll
    for (int c = 0; c < 2; ++c) {
      bf16x8 kf = *(const bf16x8*)(Kc + key * 64 + ((c * 32 + lg * 8) ^ swz));
#pragma unroll
      for (int s = S0; s < 2; ++s)
        p[s][g] = MFMA16(kf, qf[s][c], p[s][g], 0, 0, 0);
    }
  }
  __builtin_amdgcn_s_setprio(0);

  if (TWO && mask0) {
#pragma unroll
    for (int g = 0; g < 4; ++g)
#pragma unroll
      for (int r = 0; r < 4; ++r)
        if (kv0 + g * 16 + lg * 4 + r > q0row) p[0][g][r] = -1e30f;
  }
  if (mask1) {
#pragma unroll
    for (int g = 0; g < 4; ++g)
#pragma unroll
      for (int r = 0; r < 4; ++r)
        if (kv0 + g * 16 + lg * 4 + r > q1row) p[1][g][r] = -1e30f;
  }

  const float SM_NMC = -SM_M * SM_C;
  unsigned pk[2][4][2];
#pragma unroll
  for (int s = S0; s < 2; ++s) {
    float e[4][4];
#pragma unroll
    for (int g = 0; g < 4; ++g)
#pragma unroll
      for (int r = 0; r < 4; ++r)
        e[g][r] = __builtin_amdgcn_exp2f(__builtin_fmaf(p[s][g][r], SM_C, SM_NMC));
    float t0 = (e[0][0] + e[0][1]) + (e[0][2] + e[0][3]);
    float t1 = (e[1][0] + e[1][1]) + (e[1][2] + e[1][3]);
    float t2 = (e[2][0] + e[2][1]) + (e[2][2] + e[2][3]);
    float t3 = (e[3][0] + e[3][1]) + (e[3][2] + e[3][3]);
    l_r[s] += (t0 + t1) + (t2 + t3);
#pragma unroll
    for (int g = 0; g < 4; ++g) {
      pk[s][g][0] = cvtpk(e[g][0], e[g][1]);
      pk[s][g][1] = cvtpk(e[g][2], e[g][3]);
    }
  }

#pragma unroll
  for (int sl = 0; sl < 2; ++sl) {
    bf16x8 vf[4];
#pragma unroll
    for (int n = 0; n < 4; ++n) {
      const int hd = n * 16 + lr;
      vf[n] = *(const bf16x8*)(Vc + hd * 64 + ((sl * 32 + lg * 8) ^ ((hd & 7) << 3)));
    }
    __builtin_amdgcn_s_setprio(1);
#pragma unroll
    for (int s = S0; s < 2; ++s) {
      uint4v pw = {pk[s][2 * sl][0], pk[s][2 * sl][1], pk[s][2 * sl + 1][0], pk[s][2 * sl + 1][1]};
      bf16x8 pa = __builtin_bit_cast(bf16x8, pw);
#pragma unroll
      for (int n = 0; n < 4; ++n)
        cacc[s][n] = MFMA16(pa, vf[n], cacc[s][n], 0, 0, 0);
    }
    __builtin_amdgcn_s_setprio(0);
  }
}

// ---------------- Flash attention (paired strips, XCD head-grouping) --------
// Block decode groups 8 heads per XCD (bh = xcd*8 + ...): each XCD's L2 then
// holds exactly 8 heads' K+V (8 x 512KB = 4MB = one XCD L2) -> staging loads
// become L2 hits (~200cy) instead of HBM (~900cy) on re-reads across qt.
__global__ __launch_bounds__(256, 4) void flash_attn(const unsigned short* __restrict__ Qp,
                                                     const unsigned short* __restrict__ Kp,
                                                     const unsigned short* __restrict__ Vt,
                                                     unsigned short* __restrict__ Ctx) {
  __shared__ alignas(16) unsigned short Ks[2][64 * 64];
  __shared__ alignas(16) unsigned short Vs[2][64 * 64];
  const int bid = blockIdx.x;
  const int xcd = bid & 7;
  const int rest = bid >> 3;
  const int bh = xcd * 8 + (rest & 7);
  const int qt = rest >> 3;
  const int b = bh >> 4, h = bh & 15;
  const int t = threadIdx.x, l = t & 63, w = t >> 6;
  const int lr = l & 15, lg = l >> 4;
  const long rowbase = (long)b * 2048;
  const int colbase = h * 64;
  const int q0 = qt * 64 + w * 16;
  const int q1 = (31 - qt) * 64 + w * 16;
  const int q0row = q0 + lr, q1row = q1 + lr;
  const int nkv = 32 - qt;

  bf16x8 qf[2][2];
#pragma unroll
  for (int c = 0; c < 2; ++c) {
    qf[0][c] = *(const bf16x8*)(Qp + (rowbase + q0 + lr) * 1024 + colbase + c * 32 + lg * 8);
    qf[1][c] = *(const bf16x8*)(Qp + (rowbase + q1 + lr) * 1024 + colbase + c * 32 + lg * 8);
  }

  f32x4 cacc[2][4];
  float l_r[2];
#pragma unroll
  for (int s = 0; s < 2; ++s) {
    l_r[s] = 0.f;
#pragma unroll
    for (int n = 0; n < 4; ++n) cacc[s][n] = f32x4{0.f, 0.f, 0.f, 0.f};
  }

  const int srow = w * 16 + (l >> 3);
  const int scol = (l & 7) * 8;
  const int kswz = scol ^ ((srow & 7) << 3);
  const unsigned short* kp = Kp + (rowbase + srow) * 1024 + colbase + kswz;
  const unsigned short* vp = Vt + ((long)(bh * 64 + srow)) * 2048 + kswz;
  unsigned short* ksd0 = &Ks[0][(w * 16) * 64];
  unsigned short* vsd0 = &Vs[0][(w * 16) * 64];

#define STAGE(buf)                                    \
  do {                                                \
    gload16(kp, ksd0 + (buf) * 4096);                 \
    gload16(kp + 8 * 1024, ksd0 + (buf) * 4096 + 512);\
    gload16(vp, vsd0 + (buf) * 4096);                 \
    gload16(vp + 8 * 2048, vsd0 + (buf) * 4096 + 512);\
    kp += 64 * 1024;                                  \
    vp += 64;                                         \
  } while (0)

#define TILE_WAIT(j)                                                          \
  do {                                                                        \
    if ((j) == nkv - 1) asm volatile("s_waitcnt vmcnt(0)" ::: "memory");      \
    else                asm volatile("s_waitcnt vmcnt(4)" ::: "memory");      \
    asm volatile("s_barrier" ::: "memory");                                   \
  } while (0)

  STAGE(0);
  STAGE(1);

  int j = 0;
  for (; j <= qt; ++j) {  // both strips active
    const int cur = j & 1;
    TILE_WAIT(j);
    attn_tile<1>(Ks[cur], Vs[cur], lr, lg, j == qt, false, j * 64, q0row, q1row,
                 qf, cacc, l_r);
    asm volatile("s_barrier" ::: "memory");
    if (j + 2 < nkv) STAGE(cur);
  }
  for (; j < nkv; ++j) {  // long strip only
    const int cur = j & 1;
    TILE_WAIT(j);
    attn_tile<0>(Ks[cur], Vs[cur], lr, lg, false, j == nkv - 1, j * 64, q0row, q1row,
                 qf, cacc, l_r);
    asm volatile("s_barrier" ::: "memory");
    if (j + 2 < nkv) STAGE(cur);
  }
#undef STAGE
#undef TILE_WAIT

#pragma unroll
  for (int s = 0; s < 2; ++s) {
    float rs = l_r[s];
    rs += __shfl_xor(rs, 16);
    rs += __shfl_xor(rs, 32);
    float invl = 1.f / rs;
    float ilq[4];
#pragma unroll
    for (int r = 0; r < 4; ++r) ilq[r] = __shfl(invl, lg * 20 + r);
    const int qs = (s == 0) ? q0 : q1;
#pragma unroll
    for (int n = 0; n < 4; ++n)
#pragma unroll
      for (int r = 0; r < 4; ++r) {
        long row = rowbase + qs + lg * 4 + r;
        Ctx[row * 1024 + colbase + n * 16 + lr] = f2bf(cacc[s][n][r] * ilq[r]);
      }
  }
}

extern "C" void kernel_launch(void* const* d_in, const int* in_sizes, int n_in,
                              void* d_out, int out_size, void* d_ws, size_t ws_size,
                              hipStream_t stream) {
  (void)in_sizes; (void)n_in; (void)out_size; (void)ws_size;
  const float* x  = (const float*)d_in[0];
  const float* Wq = (const float*)d_in[1];
  const float* Wk = (const float*)d_in[2];
  const float* Wv = (const float*)d_in[3];
  const float* Wo = (const float*)d_in[4];
  const float* bo = (const float*)d_in[5];
  float* out = (float*)d_out;

  unsigned short* ws = (unsigned short*)d_ws;
  unsigned short* xb  = ws;                       // 8192*1024 bf16
  unsigned short* WqT = ws + 8388608;             // 4x 1024*1024 (Wq,Wk,Wv,Wo)
  unsigned short* WoT = WqT + 3145728;
  unsigned short* QKV = WqT + 4194304;            // 3 planes: Q | K | V^T (8M each)
  unsigned short* Qp  = QKV;
  unsigned short* Kp  = QKV + 8388608;
  unsigned short* Vt  = QKV + 16777216;
  unsigned short* Ctx = QKV + 25165824;           // 8192*1024

  // fused x->bf16 + 4x weight transpose (one launch)
  prep<<<6144, 256, 0, stream>>>(x, xb, Wq, Wk, Wv, Wo, WqT);

  // fused QKV projection: M=8192, N=3072, K=1024 (256x192 tiles, 512 blocks =
  // 2 exact rounds); outputs routed to Q / K / V^T planes in the epilogue.
  gemm3b<3, 0><<<512, 512, 0, stream>>>(xb, WqT, QKV, nullptr, nullptr,
                                        8192, 3072, 1024);

  // flash attention: 64 bh x 16 paired-strip blocks (XCD head-grouped)
  flash_attn<<<1024, 256, 0, stream>>>(Qp, Kp, Vt, Ctx);

  // output projection + bias: fp32 out (256x128 tiles, 256 blocks = 1 round)
  gemm3b<2, 1><<<256, 512, 0, stream>>>(Ctx, WoT, nullptr, out, bo,
                                        8192, 1024, 1024);
}